// Round 3
// baseline (211.880 us; speedup 1.0000x reference)
//
#include <hip/hip_runtime.h>
#include <math.h>

#define HH 48
#define STR 49

#define EPSF     1e-6f
#define INVF     0.54132327f          // log(exp(1-1e-6)-1) in double, rounded
#define LOG1MEPS (-1.0000005e-6f)     // log(1-1e-6)

static __device__ __forceinline__ float wred_max(float v){
#pragma unroll
  for (int m = 32; m; m >>= 1) v = fmaxf(v, __shfl_xor(v, m, 64));
  return v;
}
static __device__ __forceinline__ float wred_sum(float v){
#pragma unroll
  for (int m = 32; m; m >>= 1) v += __shfl_xor(v, m, 64);
  return v;
}
static __device__ __forceinline__ float softplusf(float z){
  return fmaxf(z, 0.0f) + log1pf(expf(-fabsf(z)));
}

// ---------------- kernel 1: x-chain (uses only s=0), one wave per b -------
__global__ __launch_bounds__(64) void dsf_xchain(
    const float* __restrict__ params, const float* __restrict__ xin,
    const float* __restrict__ w_mid, const float* __restrict__ u_last,
    const float* __restrict__ w_last, float* __restrict__ ws,
    float* __restrict__ out_x)
{
  __shared__ float Wm[3][HH*STR];   // exp(w_mid[i]), stride-49 padded
  __shared__ float Uu[HH*STR];      // exp(u_last)
  __shared__ float wl[HH];
  __shared__ float4 pk[HH];

  for (int idx = threadIdx.x; idx < 3*HH*HH; idx += 64){
    int i = idx / (HH*HH), rem = idx % (HH*HH);
    Wm[i][(rem/HH)*STR + (rem%HH)] = expf(w_mid[idx]);
  }
  for (int idx = threadIdx.x; idx < HH*HH; idx += 64){
    Uu[(idx/HH)*STR + (idx%HH)] = expf(u_last[idx]);
  }
  if (threadIdx.x < HH) wl[threadIdx.x] = w_last[threadIdx.x];
  __syncthreads();

  const int lane = threadIdx.x;
  const bool act = lane < HH;
  const int jj = act ? lane : (HH-1);
  const int b = blockIdx.x;
  const float* p = params + (size_t)b * 256 * 768;   // s = 0 row

  float X  = xin[b];
  float xn = 0.0f;

#pragma unroll
  for (int L = 0; L < 3; ++L){
    const float* q = p + L*192;
    float d0 = q[jj], d1 = q[HH+jj], d2 = q[2*HH+jj];
    float a  = softplusf(d0 + INVF) + EPSF;
    float ps = fmaf(a, X, d1);
    float sg = 1.0f / (1.0f + expf(-ps));
    float M2 = wred_max(act ? d2 : -INFINITY);
    float e  = act ? expf(d2 - M2) : 0.0f;
    if (act) pk[lane] = make_float4(e, e*sg, 0.0f, 0.0f);
    __syncthreads();
    float t0 = 0.0f, t1 = 0.0f;
    const float* Wr = &Wm[L][jj*STR];
#pragma unroll 8
    for (int j = 0; j < HH; ++j){
      float wv = Wr[j];
      float4 qv = pk[j];
      t0 = fmaf(wv, qv.x, t0);
      t1 = fmaf(wv, qv.y, t1);
    }
    __syncthreads();
    float xp = t1 / t0;                      // softmax(w+d2) . sigm  (scale cancels)
    float xc = fmaf(xp, 1.0f - EPSF, 0.5f*EPSF);
    xn = logf(xc) - logf(1.0f - xc);
    if (L == 0){
      X = wred_sum(act ? xn : 0.0f);
      if (lane == 0) ws[b] = X;              // X1
    } else if (L == 1){
      X = wred_sum(act ? xn : 0.0f);
      if (lane == 0) ws[64 + b] = X;         // X2
    } else {
      if (act) ws[128 + b*HH + lane] = xn;   // xvec2
    }
  }

  // last layer: only the x output
  const float* q = p + 3*192;
  float d0 = q[jj], d1 = q[HH+jj], d2 = q[2*HH+jj], d3 = q[3*HH+jj];
  float M3 = wred_max(act ? d3 : -INFINITY);
  float e3 = act ? expf(d3 - M3) : 0.0f;
  if (act) pk[lane] = make_float4(e3, e3*xn, 0.0f, 0.0f);
  __syncthreads();
  float s0 = 0.0f, s1 = 0.0f;
  const float* Ur = &Uu[jj*STR];
#pragma unroll 8
  for (int k = 0; k < HH; ++k){
    float uv = Ur[k];
    float4 qv = pk[k];
    s0 = fmaf(uv, qv.x, s0);
    s1 = fmaf(uv, qv.y, s1);
  }
  float dotx = s1 / s0;                      // softmax(u+d3) . xvec2
  float a  = softplusf(d0 + INVF) + EPSF;
  float ps = fmaf(a, dotx, d1);
  float sg = 1.0f / (1.0f + expf(-ps));
  float pw = wl[jj] + d2;
  float Mw = wred_max(act ? pw : -INFINITY);
  float ew = act ? expf(pw - Mw) : 0.0f;
  float Z  = wred_sum(ew);
  float xp = wred_sum(ew * sg) / Z;
  float xc = fmaf(xp, 1.0f - EPSF, 0.5f*EPSF);
  if (lane == 0) out_x[b] = logf(xc) - logf(1.0f - xc);
}

// ---------------- kernel 2: logdet for all (b,s), one wave per pair -------
__global__ __launch_bounds__(256) void dsf_logdet(
    const float* __restrict__ params, const float* __restrict__ xin,
    const float* __restrict__ w_mid, const float* __restrict__ u_last,
    const float* __restrict__ w_last, const float* __restrict__ ws,
    float* __restrict__ out_ld)
{
  __shared__ float Wm[3][HH*STR];
  __shared__ float Uu[HH*STR];
  __shared__ float wl[HH];
  __shared__ float4 pk[4][HH];

  for (int idx = threadIdx.x; idx < 3*HH*HH; idx += 256){
    int i = idx / (HH*HH), rem = idx % (HH*HH);
    Wm[i][(rem/HH)*STR + (rem%HH)] = expf(w_mid[idx]);
  }
  for (int idx = threadIdx.x; idx < HH*HH; idx += 256){
    Uu[(idx/HH)*STR + (idx%HH)] = expf(u_last[idx]);
  }
  if (threadIdx.x < HH) wl[threadIdx.x] = w_last[threadIdx.x];
  __syncthreads();

  const int wid  = threadIdx.x >> 6;
  const int lane = threadIdx.x & 63;
  const int gw   = (blockIdx.x << 2) + wid;   // b*256 + s
  const int b    = gw >> 8;
  const bool act = lane < HH;
  const int jj   = act ? lane : (HH-1);
  const float* p = params + (size_t)gw * 768;
  float4* mypk = pk[wid];

  const float Xarr[3] = { xin[b], ws[b], ws[64 + b] };
  float ld = 0.0f;   // running logdet vector, lane r holds entry r

#pragma unroll
  for (int L = 0; L < 3; ++L){
    const float* q = p + L*192;
    float d0 = q[jj], d1 = q[HH+jj], d2 = q[2*HH+jj];
    float a  = softplusf(d0 + INVF) + EPSF;
    float ps = fmaf(a, Xarr[L], d1);
    float sg = 1.0f / (1.0f + expf(-ps));
    float ap = fabsf(ps);
    // S_j = logsig(ps)+logsig(-ps)+logc(a) = -|ps| - 2*log1p(exp(-|ps|)) + 2eps + log(a)
    float S  = -ap - 2.0f*log1pf(expf(-ap)) + 2.0f*EPSF + logf(a);
    float M2 = wred_max(act ? d2 : -INFINITY);
    float Ms = wred_max(act ? (d2 + S) : -INFINITY);
    float e  = act ? expf(d2 - M2) : 0.0f;
    float e2 = act ? expf(d2 + S - Ms) : 0.0f;
    if (act) mypk[lane] = make_float4(e, e*sg, e2, 0.0f);
    __syncthreads();
    float t0 = 0.0f, t1 = 0.0f, t2 = 0.0f;
    const float* Wr = &Wm[L][jj*STR];
#pragma unroll 8
    for (int j = 0; j < HH; ++j){
      float wv = Wr[j];
      float4 qv = mypk[j];
      t0 = fmaf(wv, qv.x, t0);
      t1 = fmaf(wv, qv.y, t1);
      t2 = fmaf(wv, qv.z, t2);
    }
    __syncthreads();
    float xp  = t1 / t0;
    float xc  = fmaf(xp, 1.0f - EPSF, 0.5f*EPSF);
    float lxc = logf(xc), lxm = logf(1.0f - xc);
    float lj2 = (Ms + logf(t2)) - (M2 + logf(t0));   // logsumexp_j(logsm_w + S)
    float lsep = 0.0f;
    if (L > 0){
      float mp = wred_max(act ? ld : -INFINITY);
      float sm = wred_sum(act ? expf(ld - mp) : 0.0f);
      lsep = mp + logf(sm);
    }
    ld = lj2 + LOG1MEPS - lxc - lxm + lsep;
  }

  // ---- last layer ----
  {
    const float* q = p + 3*192;
    float d0 = q[jj], d1 = q[HH+jj], d2 = q[2*HH+jj], d3 = q[3*HH+jj];
    float M3 = wred_max(act ? d3 : -INFINITY);
    float e3 = act ? expf(d3 - M3) : 0.0f;
    float xv = ws[128 + b*HH + jj];
    if (act) mypk[lane] = make_float4(e3, e3*xv, 0.0f, 0.0f);
    __syncthreads();
    float s0 = 0.0f, s1 = 0.0f;
    const float* Ur = &Uu[jj*STR];
#pragma unroll 8
    for (int k = 0; k < HH; ++k){
      float uv = Ur[k];
      float4 qv = mypk[k];
      s0 = fmaf(uv, qv.x, s0);
      s1 = fmaf(uv, qv.y, s1);
    }
    float dotx = s1 / s0;
    float lseu = M3 + logf(s0);               // logsumexp_k(u[r,k]+d3[k])
    float a  = softplusf(d0 + INVF) + EPSF;
    float ps = fmaf(a, dotx, d1);
    float sg = 1.0f / (1.0f + expf(-ps));
    float ap = fabsf(ps);
    float Sp = -ap - 2.0f*log1pf(expf(-ap)) + 2.0f*EPSF + logf(a);
    float pw = wl[jj] + d2;
    float Mw = wred_max(act ? pw : -INFINITY);
    float ew = act ? expf(pw - Mw) : 0.0f;
    float Z  = wred_sum(ew);
    float xp = wred_sum(ew * sg) / Z;
    float lsew = Mw + logf(Z);
    float xc  = fmaf(xp, 1.0f - EPSF, 0.5f*EPSF);
    float lxc = logf(xc), lxm = logf(1.0f - xc);
    // c_j = logsm_w[j] + Sp_j - lseu_j ;  logj2[k] = d3_k + LSE_j(c_j + u[j,k])
    float c  = (pw - lsew) + Sp - lseu;
    float Mc = wred_max(act ? c : -INFINITY);
    float ec = act ? expf(c - Mc) : 0.0f;
    __syncthreads();
    if (act) mypk[lane].x = ec;
    __syncthreads();
    float acc = 0.0f;
#pragma unroll 8
    for (int j = 0; j < HH; ++j){
      acc = fmaf(mypk[j].x, Uu[j*STR + jj], acc);   // lane k reads column k: conflict-free
    }
    float lj2k = d3 + Mc + logf(acc);
    float tot  = act ? (lj2k + LOG1MEPS - lxc - lxm + ld) : -INFINITY;
    float Mt = wred_max(tot);
    float sm = wred_sum(act ? expf(tot - Mt) : 0.0f);
    if (lane == 0) out_ld[gw] = Mt + logf(sm);
  }
}

extern "C" void kernel_launch(void* const* d_in, const int* in_sizes, int n_in,
                              void* d_out, int out_size, void* d_ws, size_t ws_size,
                              hipStream_t stream) {
  const float* params = (const float*)d_in[0];   // (64,256,768)
  const float* xin    = (const float*)d_in[1];   // (64,1)
  // d_in[2] = u_mid: provably unused (softmax over size-1 axis)
  const float* w_mid  = (const float*)d_in[3];   // (3,48,48)
  const float* u_last = (const float*)d_in[4];   // (48,48)
  const float* w_last = (const float*)d_in[5];   // (1,48)
  float* out = (float*)d_out;                    // [64 x] ++ [64*256 logdet]
  float* ws  = (float*)d_ws;                     // [64 X1][64 X2][64*48 xvec2]

  hipLaunchKernelGGL(dsf_xchain, dim3(64), dim3(64), 0, stream,
                     params, xin, w_mid, u_last, w_last, ws, out);
  hipLaunchKernelGGL(dsf_logdet, dim3(4096), dim3(256), 0, stream,
                     params, xin, w_mid, u_last, w_last, ws, out + 64);
}

// Round 4
// 187.918 us; speedup vs baseline: 1.1275x; 1.1275x over previous
//
#include <hip/hip_runtime.h>
#include <math.h>
#include <stdint.h>

#define HH   48
#define RSW  25            // u32 words per packed-bf16 matrix row (24 data + 1 pad: odd stride -> 2-way banks = free)
#define MATW (HH*RSW)      // 1200 u32 per 48x48 matrix

#define EPSF     1e-6f
#define INVF     0.54132327f          // log(exp(1-1e-6)-1)
#define LOG1MEPS (-1.0000005e-6f)     // log(1-1e-6)

static __device__ __forceinline__ float fexp(float x){ return __expf(x); }
static __device__ __forceinline__ float flog(float x){ return __logf(x); }
static __device__ __forceinline__ float frcp(float x){
  float r = __builtin_amdgcn_rcpf(x);
  return r * (2.0f - x * r);          // 1 Newton step: rel err ~2^-27; args kept finite by callers
}
static __device__ __forceinline__ float wred_max(float v){
#pragma unroll
  for (int m = 32; m; m >>= 1) v = fmaxf(v, __shfl_xor(v, m, 64));
  return v;
}
static __device__ __forceinline__ float wred_sum(float v){
#pragma unroll
  for (int m = 32; m; m >>= 1) v += __shfl_xor(v, m, 64);
  return v;
}
static __device__ __forceinline__ float fsoftplus(float z){
  return fmaxf(z, 0.0f) + flog(1.0f + fexp(-fabsf(z)));
}
static __device__ __forceinline__ uint32_t bf16_rne(float x){
  uint32_t u = __float_as_uint(x);
  return (u + 0x7fffu + ((u >> 16) & 1u)) >> 16;
}
static __device__ __forceinline__ float bf_lo(uint32_t w){ return __uint_as_float(w << 16); }
static __device__ __forceinline__ float bf_hi(uint32_t w){ return __uint_as_float(w & 0xffff0000u); }

// Stage c = exp(w)-1 (packed bf16 pairs) for the 3 w_mid matrices + u_last.
// Exact decomposition: sum_j exp(w_rj+v_j) = E + sum_j c_rj * exp(v_j); c in bf16 keeps
// ~8 significant bits of the RESIDUAL -> abs error in logs ~1e-4 (threshold is 6.84).
template<int NT>
static __device__ __forceinline__ void init_cmats(uint32_t* CW,
    const float* __restrict__ w_mid, const float* __restrict__ u_last, int tid){
  for (int w = tid; w < 4*HH*24; w += NT){
    int m   = w / (HH*24);
    int rem = w - m*(HH*24);
    int r   = rem / 24, t = rem - r*24;
    const float* src = (m < 3) ? (w_mid + m*HH*HH + r*HH + 2*t)
                               : (u_last + r*HH + 2*t);
    uint32_t b0 = bf16_rne(fexp(src[0]) - 1.0f);
    uint32_t b1 = bf16_rne(fexp(src[1]) - 1.0f);
    CW[m*MATW + r*RSW + t] = b0 | (b1 << 16);
  }
}

// ---------------- kernel 1: x-chain (s=0 only), 16 blocks x 4 waves, wave per b ----
__global__ __launch_bounds__(256) void dsf_xchain(
    const float* __restrict__ params, const float* __restrict__ xin,
    const float* __restrict__ w_mid, const float* __restrict__ u_last,
    const float* __restrict__ w_last, float* __restrict__ ws,
    float* __restrict__ out_x)
{
  __shared__ uint32_t CW[4*MATW];
  __shared__ float4 pk[4][HH];

  init_cmats<256>(CW, w_mid, u_last, threadIdx.x);
  __syncthreads();

  const int wid  = threadIdx.x >> 6;
  const int lane = threadIdx.x & 63;
  const int b    = (blockIdx.x << 2) + wid;
  const bool act = lane < HH;
  const int jj   = act ? lane : (HH-1);
  const float* p = params + (size_t)b * 256 * 768;   // s = 0 row
  float4* mypk = pk[wid];

  float X  = xin[b];
  float xn = 0.0f;

#pragma unroll
  for (int L = 0; L < 3; ++L){
    const float* q = p + L*192;
    float d0 = q[jj], d1 = q[HH+jj], d2 = q[2*HH+jj];
    float a  = fsoftplus(d0 + INVF) + EPSF;
    float ps = fmaf(a, X, d1);
    float sg = frcp(1.0f + fexp(fminf(-ps, 88.0f)));   // clamp: avoid inf -> NaN in NR
    float e  = act ? fexp(d2) : 0.0f;                  // d2 raw param: no max-sub needed
    float E0 = wred_sum(e);
    float E1 = wred_sum(e * sg);
    if (act) mypk[lane] = make_float4(e, e*sg, 0.0f, 0.0f);
    __syncthreads();
    float t0 = E0, t1 = E1;
    const uint32_t* Cr = CW + L*MATW + jj*RSW;
#pragma unroll
    for (int t = 0; t < 24; ++t){
      uint32_t cw = Cr[t];
      float c0 = bf_lo(cw), c1 = bf_hi(cw);
      float4 q0 = mypk[2*t], q1 = mypk[2*t+1];
      t0 = fmaf(c0, q0.x, fmaf(c1, q1.x, t0));
      t1 = fmaf(c0, q0.y, fmaf(c1, q1.y, t1));
    }
    __syncthreads();
    float xp = fminf(fmaxf(t1 * frcp(t0), 0.0f), 1.0f);
    float xc = fmaf(xp, 1.0f - EPSF, 0.5f*EPSF);
    xn = flog(xc) - flog(1.0f - xc);
    if (L == 0){ X = wred_sum(act ? xn : 0.0f); if (lane == 0) ws[b] = X; }
    else if (L == 1){ X = wred_sum(act ? xn : 0.0f); if (lane == 0) ws[64 + b] = X; }
    else { if (act) ws[128 + b*HH + lane] = xn; }
  }

  // last layer: x output only
  const float* q = p + 3*192;
  float d0 = q[jj], d1 = q[HH+jj], d2 = q[2*HH+jj], d3 = q[3*HH+jj];
  float e3 = act ? fexp(d3) : 0.0f;
  float E30 = wred_sum(e3);
  float E31 = wred_sum(e3 * xn);
  if (act) mypk[lane] = make_float4(e3, e3*xn, 0.0f, 0.0f);
  __syncthreads();
  float s0 = E30, s1 = E31;
  const uint32_t* Ur = CW + 3*MATW + jj*RSW;
#pragma unroll
  for (int t = 0; t < 24; ++t){
    uint32_t cw = Ur[t];
    float c0 = bf_lo(cw), c1 = bf_hi(cw);
    float4 q0 = mypk[2*t], q1 = mypk[2*t+1];
    s0 = fmaf(c0, q0.x, fmaf(c1, q1.x, s0));
    s1 = fmaf(c0, q0.y, fmaf(c1, q1.y, s1));
  }
  float dotx = s1 * frcp(s0);
  float a  = fsoftplus(d0 + INVF) + EPSF;
  float ps = fmaf(a, dotx, d1);
  float sg = frcp(1.0f + fexp(fminf(-ps, 88.0f)));
  float pw = w_last[jj] + d2;
  float ew = act ? fexp(pw) : 0.0f;
  float Z  = wred_sum(ew);
  float xp = fminf(fmaxf(wred_sum(ew * sg) * frcp(Z), 0.0f), 1.0f);
  float xc = fmaf(xp, 1.0f - EPSF, 0.5f*EPSF);
  if (lane == 0) out_x[b] = flog(xc) - flog(1.0f - xc);
}

// ---------------- kernel 2: logdet, one wave per (b,s) ----------------------------
__global__ __launch_bounds__(256, 7) void dsf_logdet(
    const float* __restrict__ params, const float* __restrict__ xin,
    const float* __restrict__ w_mid, const float* __restrict__ u_last,
    const float* __restrict__ w_last, const float* __restrict__ ws,
    float* __restrict__ out_ld)
{
  __shared__ uint32_t CW[4*MATW];   // 19200 B
  __shared__ float4 pk[4][HH];      // 3072 B
  __shared__ float wl[HH];          // total ~22.5 KB -> 7 blocks/CU

  init_cmats<256>(CW, w_mid, u_last, threadIdx.x);
  if (threadIdx.x < HH) wl[threadIdx.x] = w_last[threadIdx.x];
  __syncthreads();

  const int wid  = threadIdx.x >> 6;
  const int lane = threadIdx.x & 63;
  const int gw   = (blockIdx.x << 2) + wid;   // b*256 + s
  const int b    = gw >> 8;
  const bool act = lane < HH;
  const int jj   = act ? lane : (HH-1);
  const float* p = params + (size_t)gw * 768;
  float4* mypk = pk[wid];

  const float Xarr[3] = { xin[b], ws[b], ws[64 + b] };
  float ld = 0.0f;   // lane r holds logdet entry r

#pragma unroll
  for (int L = 0; L < 3; ++L){
    const float* q = p + L*192;
    float d0 = q[jj], d1 = q[HH+jj], d2 = q[2*HH+jj];
    float a  = fsoftplus(d0 + INVF) + EPSF;
    float ps = fmaf(a, Xarr[L], d1);
    float sg = frcp(1.0f + fexp(fminf(-ps, 88.0f)));
    float ap = fabsf(ps);
    // S = logsig(ps)+logsig(-ps)+logc(a)
    float S  = -ap - 2.0f*flog(1.0f + fexp(-ap)) + 2.0f*EPSF + flog(a);
    float Ms = wred_max(act ? (d2 + S) : -INFINITY);   // S can be ~ -300: keep max-sub
    float e  = act ? fexp(d2) : 0.0f;
    float f2 = act ? fexp(d2 + S - Ms) : 0.0f;
    float E0 = wred_sum(e);
    float E1 = wred_sum(e * sg);
    float E2 = wred_sum(f2);
    if (act) mypk[lane] = make_float4(e, e*sg, f2, 0.0f);
    __syncthreads();
    float t0 = E0, t1 = E1, t2 = E2;
    const uint32_t* Cr = CW + L*MATW + jj*RSW;
#pragma unroll
    for (int t = 0; t < 24; ++t){
      uint32_t cw = Cr[t];
      float c0 = bf_lo(cw), c1 = bf_hi(cw);
      float4 q0 = mypk[2*t], q1 = mypk[2*t+1];
      t0 = fmaf(c0, q0.x, fmaf(c1, q1.x, t0));
      t1 = fmaf(c0, q0.y, fmaf(c1, q1.y, t1));
      t2 = fmaf(c0, q0.z, fmaf(c1, q1.z, t2));
    }
    __syncthreads();
    float xp  = fminf(fmaxf(t1 * frcp(t0), 0.0f), 1.0f);
    float xc  = fmaf(xp, 1.0f - EPSF, 0.5f*EPSF);
    float lxc = flog(xc), lxm = flog(1.0f - xc);
    float lj2 = Ms + flog(t2) - flog(t0);     // LSE_j(logsm_w + S)
    float lsep = 0.0f;
    if (L > 0){
      float mp = wred_max(act ? ld : -INFINITY);
      float sm = wred_sum(act ? fexp(ld - mp) : 0.0f);
      lsep = mp + flog(sm);
    }
    ld = lj2 + LOG1MEPS - lxc - lxm + lsep;
  }

  // ---- last layer ----
  {
    const float* q = p + 3*192;
    float d0 = q[jj], d1 = q[HH+jj], d2 = q[2*HH+jj], d3 = q[3*HH+jj];
    float e3 = act ? fexp(d3) : 0.0f;
    float xv = ws[128 + b*HH + jj];
    float E30 = wred_sum(e3);
    float E31 = wred_sum(e3 * xv);
    if (act) mypk[lane] = make_float4(e3, e3*xv, 0.0f, 0.0f);
    __syncthreads();
    float s0 = E30, s1 = E31;
    const uint32_t* Ur = CW + 3*MATW + jj*RSW;
#pragma unroll
    for (int t = 0; t < 24; ++t){
      uint32_t cw = Ur[t];
      float c0 = bf_lo(cw), c1 = bf_hi(cw);
      float4 q0 = mypk[2*t], q1 = mypk[2*t+1];
      s0 = fmaf(c0, q0.x, fmaf(c1, q1.x, s0));
      s1 = fmaf(c0, q0.y, fmaf(c1, q1.y, s1));
    }
    float dotx = s1 * frcp(s0);
    float lseu = flog(s0);                    // LSE_k(u[r,k]+d3[k])
    float a  = fsoftplus(d0 + INVF) + EPSF;
    float ps = fmaf(a, dotx, d1);
    float sg = frcp(1.0f + fexp(fminf(-ps, 88.0f)));
    float ap = fabsf(ps);
    float Sp = -ap - 2.0f*flog(1.0f + fexp(-ap)) + 2.0f*EPSF + flog(a);
    float pw = wl[jj] + d2;
    float ew = act ? fexp(pw) : 0.0f;
    float Z  = wred_sum(ew);
    float xp = fminf(fmaxf(wred_sum(ew * sg) * frcp(Z), 0.0f), 1.0f);
    float lsew = flog(Z);
    float xc  = fmaf(xp, 1.0f - EPSF, 0.5f*EPSF);
    float lxc = flog(xc), lxm = flog(1.0f - xc);
    // c_j = logsm_w[j] + Sp_j - lseu_j ; logj2[k] = d3_k + LSE_j(c_j + u[j,k])
    float c  = (pw - lsew) + Sp - lseu;
    float Mc = wred_max(act ? c : -INFINITY);
    float ec = act ? fexp(c - Mc) : 0.0f;
    float Ec = wred_sum(ec);
    __syncthreads();
    if (act) mypk[lane].x = ec;
    __syncthreads();
    // transposed matvec: lane k: acc = Ec + sum_j ec_j * cU[j][k]
    const uint32_t sh = (jj & 1) ? 0u : 16u;
    const int kw = jj >> 1;
    float acc = Ec;
#pragma unroll 8
    for (int j = 0; j < HH; ++j){
      uint32_t cw = CW[3*MATW + j*RSW + kw];
      float cc = __uint_as_float((cw << sh) & 0xffff0000u);
      acc = fmaf(mypk[j].x, cc, acc);
    }
    float lj2k = d3 + Mc + flog(acc);
    float tot  = act ? (lj2k + LOG1MEPS - lxc - lxm + ld) : -INFINITY;
    float Mt = wred_max(tot);
    float sm = wred_sum(act ? fexp(tot - Mt) : 0.0f);
    if (lane == 0) out_ld[gw] = Mt + flog(sm);
  }
}

extern "C" void kernel_launch(void* const* d_in, const int* in_sizes, int n_in,
                              void* d_out, int out_size, void* d_ws, size_t ws_size,
                              hipStream_t stream) {
  const float* params = (const float*)d_in[0];   // (64,256,768)
  const float* xin    = (const float*)d_in[1];   // (64,1)
  // d_in[2] = u_mid: provably unused (softmax over size-1 axis)
  const float* w_mid  = (const float*)d_in[3];   // (3,48,48)
  const float* u_last = (const float*)d_in[4];   // (48,48)
  const float* w_last = (const float*)d_in[5];   // (1,48)
  float* out = (float*)d_out;                    // [64 x] ++ [64*256 logdet]
  float* ws  = (float*)d_ws;                     // [64 X1][64 X2][64*48 xvec2]

  hipLaunchKernelGGL(dsf_xchain, dim3(16), dim3(256), 0, stream,
                     params, xin, w_mid, u_last, w_last, ws, out);
  hipLaunchKernelGGL(dsf_logdet, dim3(4096), dim3(256), 0, stream,
                     params, xin, w_mid, u_last, w_last, ws, out + 64);
}

// Round 9
// 180.127 us; speedup vs baseline: 1.1763x; 1.0432x over previous
//
#include <hip/hip_runtime.h>
#include <math.h>
#include <stdint.h>

#define HH   48
#define RSW  25            // u32 words per packed-bf16 matrix row (24 data + 1 pad: odd stride -> <=2-way banks = free)
#define MATW (HH*RSW)      // 1200 u32 per 48x48 matrix

#define EPSF     1e-6f
#define INVF     0.54132327f          // log(exp(1-1e-6)-1)
#define LOG1MEPS (-1.0000005e-6f)     // log(1-1e-6)

static __device__ __forceinline__ float fexp(float x){ return __expf(x); }
static __device__ __forceinline__ float flog(float x){ return __logf(x); }
static __device__ __forceinline__ float frcp(float x){
  float r = __builtin_amdgcn_rcpf(x);
  return r * (2.0f - x * r);          // 1 Newton step; args kept finite by callers
}
static __device__ __forceinline__ float wred_max(float v){
#pragma unroll
  for (int m = 32; m; m >>= 1) v = fmaxf(v, __shfl_xor(v, m, 64));
  return v;
}
static __device__ __forceinline__ float wred_sum(float v){
#pragma unroll
  for (int m = 32; m; m >>= 1) v += __shfl_xor(v, m, 64);
  return v;
}
static __device__ __forceinline__ float fsoftplus(float z){
  return fmaxf(z, 0.0f) + flog(1.0f + fexp(-fabsf(z)));
}
static __device__ __forceinline__ uint32_t bf16_rne(float x){
  uint32_t u = __float_as_uint(x);
  return (u + 0x7fffu + ((u >> 16) & 1u)) >> 16;
}
static __device__ __forceinline__ float bf_lo(uint32_t w){ return __uint_as_float(w << 16); }
static __device__ __forceinline__ float bf_hi(uint32_t w){ return __uint_as_float(w & 0xffff0000u); }

// Stage c = exp(w)-1 (packed bf16 pairs) for the 3 w_mid matrices + u_last.
// Exact decomposition: sum_j exp(w_rj+v_j) = E + sum_j c_rj * exp(v_j); c in bf16 keeps
// ~8 significant bits of the RESIDUAL -> abs error in logs ~1e-4 (threshold is 6.84).
template<int NT>
static __device__ __forceinline__ void init_cmats(uint32_t* CW,
    const float* __restrict__ w_mid, const float* __restrict__ u_last, int tid){
  for (int w = tid; w < 4*HH*24; w += NT){
    int m   = w / (HH*24);
    int rem = w - m*(HH*24);
    int r   = rem / 24, t = rem - r*24;
    const float* src = (m < 3) ? (w_mid + m*HH*HH + r*HH + 2*t)
                               : (u_last + r*HH + 2*t);
    uint32_t b0 = bf16_rne(fexp(src[0]) - 1.0f);
    uint32_t b1 = bf16_rne(fexp(src[1]) - 1.0f);
    CW[m*MATW + r*RSW + t] = b0 | (b1 << 16);
  }
}

// ---------------- kernel 1: x-chain (s=0 only), 16 blocks x 4 waves, wave per b ----
__global__ __launch_bounds__(256) void dsf_xchain(
    const float* __restrict__ params, const float* __restrict__ xin,
    const float* __restrict__ w_mid, const float* __restrict__ u_last,
    const float* __restrict__ w_last, float* __restrict__ ws,
    float* __restrict__ out_x)
{
  __shared__ uint32_t CW[4*MATW];
  __shared__ float4 pk[4][HH];

  init_cmats<256>(CW, w_mid, u_last, threadIdx.x);
  __syncthreads();

  const int wid  = threadIdx.x >> 6;
  const int lane = threadIdx.x & 63;
  const int b    = (blockIdx.x << 2) + wid;
  const bool act = lane < HH;
  const int jj   = act ? lane : (HH-1);
  const float* p = params + (size_t)b * 256 * 768;   // s = 0 row
  float4* mypk = pk[wid];

  float X  = xin[b];
  float xn = 0.0f;

#pragma unroll
  for (int L = 0; L < 3; ++L){
    const float* q = p + L*192;
    float d0 = q[jj], d1 = q[HH+jj], d2 = q[2*HH+jj];
    float a  = fsoftplus(d0 + INVF) + EPSF;
    float ps = fmaf(a, X, d1);
    float sg = frcp(1.0f + fexp(fminf(-ps, 88.0f)));   // clamp: avoid inf -> NaN in NR
    float e  = act ? fexp(d2) : 0.0f;                  // d2 raw param: no max-sub needed
    float E0 = wred_sum(e);
    float E1 = wred_sum(e * sg);
    if (act) mypk[lane] = make_float4(e, e*sg, 0.0f, 0.0f);
    __syncthreads();
    float t0 = E0, t1 = E1;
    const uint32_t* Cr = CW + L*MATW + jj*RSW;
#pragma unroll
    for (int t = 0; t < 24; ++t){
      uint32_t cw = Cr[t];
      float c0 = bf_lo(cw), c1 = bf_hi(cw);
      float4 q0 = mypk[2*t], q1 = mypk[2*t+1];
      t0 = fmaf(c0, q0.x, fmaf(c1, q1.x, t0));
      t1 = fmaf(c0, q0.y, fmaf(c1, q1.y, t1));
    }
    __syncthreads();
    float xp = fminf(fmaxf(t1 * frcp(t0), 0.0f), 1.0f);
    float xc = fmaf(xp, 1.0f - EPSF, 0.5f*EPSF);
    xn = flog(xc) - flog(1.0f - xc);
    if (L == 0){ X = wred_sum(act ? xn : 0.0f); if (lane == 0) ws[b] = X; }
    else if (L == 1){ X = wred_sum(act ? xn : 0.0f); if (lane == 0) ws[64 + b] = X; }
    else { if (act) ws[128 + b*HH + lane] = xn; }
  }

  // last layer: x output only
  const float* q = p + 3*192;
  float d0 = q[jj], d1 = q[HH+jj], d2 = q[2*HH+jj], d3 = q[3*HH+jj];
  float e3 = act ? fexp(d3) : 0.0f;
  float E30 = wred_sum(e3);
  float E31 = wred_sum(e3 * xn);
  if (act) mypk[lane] = make_float4(e3, e3*xn, 0.0f, 0.0f);
  __syncthreads();
  float s0 = E30, s1 = E31;
  const uint32_t* Ur = CW + 3*MATW + jj*RSW;
#pragma unroll
  for (int t = 0; t < 24; ++t){
    uint32_t cw = Ur[t];
    float c0 = bf_lo(cw), c1 = bf_hi(cw);
    float4 q0 = mypk[2*t], q1 = mypk[2*t+1];
    s0 = fmaf(c0, q0.x, fmaf(c1, q1.x, s0));
    s1 = fmaf(c0, q0.y, fmaf(c1, q1.y, s1));
  }
  float dotx = s1 * frcp(s0);
  float a  = fsoftplus(d0 + INVF) + EPSF;
  float ps = fmaf(a, dotx, d1);
  float sg = frcp(1.0f + fexp(fminf(-ps, 88.0f)));
  float pw = w_last[jj] + d2;
  float ew = act ? fexp(pw) : 0.0f;
  float Z  = wred_sum(ew);
  float xp = fminf(fmaxf(wred_sum(ew * sg) * frcp(Z), 0.0f), 1.0f);
  float xc = fmaf(xp, 1.0f - EPSF, 0.5f*EPSF);
  if (lane == 0) out_x[b] = flog(xc) - flog(1.0f - xc);
}

// ---------------- kernel 2: logdet, one wave per (b,s) ----------------------------
// NOTE: no min-waves bound. LDS (22.5 KB) already caps at 7 blocks/CU; a forced
// waves-per-EU bound in round 4 made the allocator spill (~45 MB scratch writes).
__global__ __launch_bounds__(256) void dsf_logdet(
    const float* __restrict__ params, const float* __restrict__ xin,
    const float* __restrict__ w_mid, const float* __restrict__ u_last,
    const float* __restrict__ w_last, const float* __restrict__ ws,
    float* __restrict__ out_ld)
{
  __shared__ uint32_t CW[4*MATW];   // 19200 B
  __shared__ float4 pk[4][HH];      // 3072 B
  __shared__ float wl[HH];          // total ~22.5 KB -> 7 blocks/CU

  init_cmats<256>(CW, w_mid, u_last, threadIdx.x);
  if (threadIdx.x < HH) wl[threadIdx.x] = w_last[threadIdx.x];
  __syncthreads();

  const int wid  = threadIdx.x >> 6;
  const int lane = threadIdx.x & 63;
  const int gw   = (blockIdx.x << 2) + wid;   // b*256 + s
  const int b    = gw >> 8;
  const bool act = lane < HH;
  const int jj   = act ? lane : (HH-1);
  const float* p = params + (size_t)gw * 768;
  float4* mypk = pk[wid];

  const float Xarr[3] = { xin[b], ws[b], ws[64 + b] };
  float ld = 0.0f;   // lane r holds logdet entry r

#pragma unroll
  for (int L = 0; L < 3; ++L){
    const float* q = p + L*192;
    float d0 = q[jj], d1 = q[HH+jj], d2 = q[2*HH+jj];
    float a  = fsoftplus(d0 + INVF) + EPSF;
    float ps = fmaf(a, Xarr[L], d1);
    float sg = frcp(1.0f + fexp(fminf(-ps, 88.0f)));
    float ap = fabsf(ps);
    // S = logsig(ps)+logsig(-ps)+logc(a)
    float S  = -ap - 2.0f*flog(1.0f + fexp(-ap)) + 2.0f*EPSF + flog(a);
    float Ms = wred_max(act ? (d2 + S) : -INFINITY);   // S can be ~ -300: keep max-sub
    float e  = act ? fexp(d2) : 0.0f;
    float f2 = act ? fexp(d2 + S - Ms) : 0.0f;
    float E0 = wred_sum(e);
    float E1 = wred_sum(e * sg);
    float E2 = wred_sum(f2);
    if (act) mypk[lane] = make_float4(e, e*sg, f2, 0.0f);
    __syncthreads();
    float t0 = E0, t1 = E1, t2 = E2;
    const uint32_t* Cr = CW + L*MATW + jj*RSW;
#pragma unroll
    for (int t = 0; t < 24; ++t){
      uint32_t cw = Cr[t];
      float c0 = bf_lo(cw), c1 = bf_hi(cw);
      float4 q0 = mypk[2*t], q1 = mypk[2*t+1];
      t0 = fmaf(c0, q0.x, fmaf(c1, q1.x, t0));
      t1 = fmaf(c0, q0.y, fmaf(c1, q1.y, t1));
      t2 = fmaf(c0, q0.z, fmaf(c1, q1.z, t2));
    }
    __syncthreads();
    float xp  = fminf(fmaxf(t1 * frcp(t0), 0.0f), 1.0f);
    float xc  = fmaf(xp, 1.0f - EPSF, 0.5f*EPSF);
    float lxc = flog(xc), lxm = flog(1.0f - xc);
    float lj2 = Ms + flog(t2) - flog(t0);     // LSE_j(logsm_w + S)
    float lsep = 0.0f;
    if (L > 0){
      float mp = wred_max(act ? ld : -INFINITY);
      float sm = wred_sum(act ? fexp(ld - mp) : 0.0f);
      lsep = mp + flog(sm);
    }
    ld = lj2 + LOG1MEPS - lxc - lxm + lsep;
  }

  // ---- last layer ----
  {
    const float* q = p + 3*192;
    float d0 = q[jj], d1 = q[HH+jj], d2 = q[2*HH+jj], d3 = q[3*HH+jj];
    float e3 = act ? fexp(d3) : 0.0f;
    float xv = ws[128 + b*HH + jj];
    float E30 = wred_sum(e3);
    float E31 = wred_sum(e3 * xv);
    if (act) mypk[lane] = make_float4(e3, e3*xv, 0.0f, 0.0f);
    __syncthreads();
    float s0 = E30, s1 = E31;
    const uint32_t* Ur = CW + 3*MATW + jj*RSW;
#pragma unroll
    for (int t = 0; t < 24; ++t){
      uint32_t cw = Ur[t];
      float c0 = bf_lo(cw), c1 = bf_hi(cw);
      float4 q0 = mypk[2*t], q1 = mypk[2*t+1];
      s0 = fmaf(c0, q0.x, fmaf(c1, q1.x, s0));
      s1 = fmaf(c0, q0.y, fmaf(c1, q1.y, s1));
    }
    float dotx = s1 * frcp(s0);
    float lseu = flog(s0);                    // LSE_k(u[r,k]+d3[k])
    float a  = fsoftplus(d0 + INVF) + EPSF;
    float ps = fmaf(a, dotx, d1);
    float sg = frcp(1.0f + fexp(fminf(-ps, 88.0f)));
    float ap = fabsf(ps);
    float Sp = -ap - 2.0f*flog(1.0f + fexp(-ap)) + 2.0f*EPSF + flog(a);
    float pw = wl[jj] + d2;
    float ew = act ? fexp(pw) : 0.0f;
    float Z  = wred_sum(ew);
    float xp = fminf(fmaxf(wred_sum(ew * sg) * frcp(Z), 0.0f), 1.0f);
    float lsew = flog(Z);
    float xc  = fmaf(xp, 1.0f - EPSF, 0.5f*EPSF);
    float lxc = flog(xc), lxm = flog(1.0f - xc);
    // c_j = logsm_w[j] + Sp_j - lseu_j ; logj2[k] = d3_k + LSE_j(c_j + u[j,k])
    float c  = (pw - lsew) + Sp - lseu;
    float Mc = wred_max(act ? c : -INFINITY);
    float ec = act ? fexp(c - Mc) : 0.0f;
    float Ec = wred_sum(ec);
    __syncthreads();
    if (act) mypk[lane].x = ec;
    __syncthreads();
    // transposed matvec: lane k: acc = Ec + sum_j ec_j * cU[j][k]
    const uint32_t sh = (jj & 1) ? 0u : 16u;
    const int kw = jj >> 1;
    float acc = Ec;
#pragma unroll 8
    for (int j = 0; j < HH; ++j){
      uint32_t cw = CW[3*MATW + j*RSW + kw];
      float cc = __uint_as_float((cw << sh) & 0xffff0000u);
      acc = fmaf(mypk[j].x, cc, acc);
    }
    float lj2k = d3 + Mc + flog(acc);
    float tot  = act ? (lj2k + LOG1MEPS - lxc - lxm + ld) : -INFINITY;
    float Mt = wred_max(tot);
    float sm = wred_sum(act ? fexp(tot - Mt) : 0.0f);
    if (lane == 0) out_ld[gw] = Mt + flog(sm);
  }
}

extern "C" void kernel_launch(void* const* d_in, const int* in_sizes, int n_in,
                              void* d_out, int out_size, void* d_ws, size_t ws_size,
                              hipStream_t stream) {
  const float* params = (const float*)d_in[0];   // (64,256,768)
  const float* xin    = (const float*)d_in[1];   // (64,1)
  // d_in[2] = u_mid: provably unused (softmax over size-1 axis)
  const float* w_mid  = (const float*)d_in[3];   // (3,48,48)
  const float* u_last = (const float*)d_in[4];   // (48,48)
  const float* w_last = (const float*)d_in[5];   // (1,48)
  float* out = (float*)d_out;                    // [64 x] ++ [64*256 logdet]
  float* ws  = (float*)d_ws;                     // [64 X1][64 X2][64*48 xvec2]

  hipLaunchKernelGGL(dsf_xchain, dim3(16), dim3(256), 0, stream,
                     params, xin, w_mid, u_last, w_last, ws, out);
  hipLaunchKernelGGL(dsf_logdet, dim3(4096), dim3(256), 0, stream,
                     params, xin, w_mid, u_last, w_last, ws, out + 64);
}